// Round 1
// baseline (1077.391 us; speedup 1.0000x reference)
//
#include <hip/hip_runtime.h>
#include <hip/hip_bf16.h>

#define NN 100000
#define EE 1600000
#define HID 128
#define CLS 40
#define EPSBN 1e-5f

// ---------------- degree / CSR build ----------------

__global__ void init_deg_counts(float* deg, int* counts, int n) {
    int i = blockIdx.x * 256 + threadIdx.x;
    if (i < n) { deg[i] = 1.0f; counts[i] = 0; }
}

__global__ void edge_count(const int* __restrict__ dst, float* deg, int* counts, int e) {
    int i = blockIdx.x * 256 + threadIdx.x;
    if (i < e) {
        int d = dst[i];
        atomicAdd(&deg[d], 1.0f);
        atomicAdd(&counts[d], 1);
    }
}

__global__ void make_dinv(float* deg, int n) {
    int i = blockIdx.x * 256 + threadIdx.x;
    if (i < n) deg[i] = rsqrtf(deg[i]);
}

__global__ __launch_bounds__(1024) void scan1(int* counts, int* blocksums, int n) {
    __shared__ int tmp[1024];
    int tid = threadIdx.x;
    int gid = blockIdx.x * 1024 + tid;
    int v = (gid < n) ? counts[gid] : 0;
    tmp[tid] = v;
    __syncthreads();
    for (int off = 1; off < 1024; off <<= 1) {
        int t = (tid >= off) ? tmp[tid - off] : 0;
        __syncthreads();
        tmp[tid] += t;
        __syncthreads();
    }
    if (gid < n) counts[gid] = tmp[tid];        // in-place inclusive per-block scan
    if (tid == 1023) blocksums[blockIdx.x] = tmp[1023];
}

__global__ void scan2(int* blocksums, int nb) {
    __shared__ int tmp[128];
    int tid = threadIdx.x;
    int v = (tid < nb) ? blocksums[tid] : 0;
    tmp[tid] = v;
    __syncthreads();
    for (int off = 1; off < 128; off <<= 1) {
        int t = (tid >= off) ? tmp[tid - off] : 0;
        __syncthreads();
        tmp[tid] += t;
        __syncthreads();
    }
    if (tid < nb) blocksums[tid] = (tid == 0) ? 0 : tmp[tid - 1];   // exclusive
}

__global__ void scan3(const int* __restrict__ incl, const int* __restrict__ blocksums,
                      int* row_ptr, int* cursor, int n) {
    int gid = blockIdx.x * 256 + threadIdx.x;
    if (gid >= n) return;
    int inc = incl[gid] + blocksums[gid >> 10];
    row_ptr[gid + 1] = inc;
    int start = (gid == 0) ? 0 : incl[gid - 1] + blocksums[(gid - 1) >> 10];
    cursor[gid] = start;
    if (gid == 0) row_ptr[0] = 0;
}

__global__ void fill_csr(const int* __restrict__ src, const int* __restrict__ dst,
                         const float* __restrict__ dinv, int* cursor,
                         int* csr_src, float* csr_coef, int e) {
    int i = blockIdx.x * 256 + threadIdx.x;
    if (i >= e) return;
    int s = src[i], d = dst[i];
    int p = atomicAdd(&cursor[d], 1);
    csr_src[p] = s;
    csr_coef[p] = dinv[s] * dinv[d];
}

// ---------------- GEMMs ----------------

// X[n x 128] @ W[128 x 128] -> H[n x 128].  32 rows/block, 256 threads, 4x4 reg tile.
__global__ __launch_bounds__(256) void gemm128(const float* __restrict__ X,
                                               const float* __restrict__ W,
                                               float* __restrict__ H) {
    __shared__ float ws[128][128];
    __shared__ float xs[32][128];
    int t = threadIdx.x;
    {
        const float4* Wv = (const float4*)W;
        float4* wsv = (float4*)&ws[0][0];
        for (int i = t; i < 128 * 128 / 4; i += 256) wsv[i] = Wv[i];
    }
    int row0 = blockIdx.x * 32;
    {
        const float4* Xv = (const float4*)(X + (size_t)row0 * 128);
        float4* xsv = (float4*)&xs[0][0];
        for (int i = t; i < 32 * 128 / 4; i += 256) xsv[i] = Xv[i];
    }
    __syncthreads();
    int tj = t & 31;     // col quad: cols 4*tj..4*tj+3
    int ti = t >> 5;     // row group: rows 4*ti..4*ti+3
    float acc[4][4] = {};
    for (int k = 0; k < 128; k += 4) {
        float4 xa[4], wb[4];
#pragma unroll
        for (int r = 0; r < 4; r++) xa[r] = *(const float4*)&xs[4 * ti + r][k];
#pragma unroll
        for (int kk = 0; kk < 4; kk++) wb[kk] = *(const float4*)&ws[k + kk][4 * tj];
#pragma unroll
        for (int kk = 0; kk < 4; kk++) {
#pragma unroll
            for (int r = 0; r < 4; r++) {
                float xv = ((const float*)&xa[r])[kk];
                acc[r][0] += xv * wb[kk].x;
                acc[r][1] += xv * wb[kk].y;
                acc[r][2] += xv * wb[kk].z;
                acc[r][3] += xv * wb[kk].w;
            }
        }
    }
#pragma unroll
    for (int r = 0; r < 4; r++) {
        float4 v = make_float4(acc[r][0], acc[r][1], acc[r][2], acc[r][3]);
        *(float4*)&H[(size_t)(row0 + 4 * ti + r) * 128 + 4 * tj] = v;
    }
}

// X[n x 128] @ W3[128 x 40] -> H[n x 40]. One row per thread.
__global__ __launch_bounds__(256) void gemm40(const float* __restrict__ X,
                                              const float* __restrict__ W3,
                                              float* __restrict__ H, int n) {
    __shared__ float ws[128][CLS];
    int t = threadIdx.x;
    for (int i = t; i < 128 * CLS; i += 256) ws[i / CLS][i % CLS] = W3[i];
    __syncthreads();
    int row = blockIdx.x * 256 + t;
    if (row >= n) return;
    const float4* xr = (const float4*)(X + (size_t)row * 128);
    float acc[CLS] = {};
    for (int kc = 0; kc < 32; kc++) {
        float4 xv = xr[kc];
#pragma unroll
        for (int kk = 0; kk < 4; kk++) {
            float x1 = ((const float*)&xv)[kk];
            int k = kc * 4 + kk;
#pragma unroll
            for (int j = 0; j < CLS; j++) acc[j] += x1 * ws[k][j];
        }
    }
#pragma unroll
    for (int j = 0; j < CLS; j++) H[(size_t)row * CLS + j] = acc[j];
}

// ---------------- aggregation ----------------

// out[node][f] = dinv[node]^2 * h[node][f] + sum_edges coef * h[src][f] + bias[f]
__global__ __launch_bounds__(128) void agg128(const float* __restrict__ h,
                                              const int* __restrict__ row_ptr,
                                              const int* __restrict__ csr_src,
                                              const float* __restrict__ csr_coef,
                                              const float* __restrict__ dinv,
                                              const float* __restrict__ bias,
                                              float* __restrict__ out) {
    int node = blockIdx.x;
    int f = threadIdx.x;
    float di = dinv[node];
    float acc = h[(size_t)node * 128 + f] * (di * di);
    int beg = row_ptr[node], end = row_ptr[node + 1];
    for (int e = beg; e < end; e++) {
        int s = csr_src[e];
        float c = csr_coef[e];
        acc += h[(size_t)s * 128 + f] * c;
    }
    out[(size_t)node * 128 + f] = acc + bias[f];
}

// layer-3 aggregation fused with bias + log_softmax; one wave (64 lanes) per node
__global__ __launch_bounds__(256) void agg40_lsm(const float* __restrict__ h3,
                                                 const int* __restrict__ row_ptr,
                                                 const int* __restrict__ csr_src,
                                                 const float* __restrict__ csr_coef,
                                                 const float* __restrict__ dinv,
                                                 const float* __restrict__ b3,
                                                 float* __restrict__ out, int n) {
    int wid = threadIdx.x >> 6;
    int lane = threadIdx.x & 63;
    int node = blockIdx.x * 4 + wid;
    if (node >= n) return;
    bool act = lane < CLS;
    float di = dinv[node];
    float acc = act ? h3[(size_t)node * CLS + lane] * (di * di) : 0.0f;
    int beg = row_ptr[node], end = row_ptr[node + 1];
    for (int e = beg; e < end; e++) {
        int s = csr_src[e];
        float c = csr_coef[e];
        if (act) acc += h3[(size_t)s * CLS + lane] * c;
    }
    if (act) acc += b3[lane];
    float m = act ? acc : -1e30f;
#pragma unroll
    for (int off = 32; off > 0; off >>= 1) m = fmaxf(m, __shfl_xor(m, off));
    float ex = act ? expf(acc - m) : 0.0f;
    float ssum = ex;
#pragma unroll
    for (int off = 32; off > 0; off >>= 1) ssum += __shfl_xor(ssum, off);
    if (act) out[(size_t)node * CLS + lane] = acc - m - logf(ssum);
}

// ---------------- batchnorm ----------------

__global__ void zero_stats(float* stats) {
    if (threadIdx.x < 256) stats[threadIdx.x] = 0.0f;
}

__global__ __launch_bounds__(128) void bn_stats(const float* __restrict__ a,
                                                float* __restrict__ stats, int n) {
    int f = threadIdx.x;
    float s = 0.0f, s2 = 0.0f;
    for (int i = blockIdx.x; i < n; i += gridDim.x) {
        float v = a[(size_t)i * 128 + f];
        s += v;
        s2 += v * v;
    }
    atomicAdd(&stats[f], s);
    atomicAdd(&stats[128 + f], s2);
}

__global__ void bn_apply(const float* __restrict__ a, const float* __restrict__ xres,
                         const float* __restrict__ g, const float* __restrict__ be,
                         const float* __restrict__ stats, float* __restrict__ o,
                         int n, int addres) {
    int gid = blockIdx.x * 256 + threadIdx.x;
    if (gid >= n * 128) return;
    int f = gid & 127;
    float mean = stats[f] * (1.0f / (float)NN);
    float var = stats[128 + f] * (1.0f / (float)NN) - mean * mean;
    float sc = g[f] * rsqrtf(var + EPSBN);
    float sh = be[f] - mean * sc;
    float v = fmaf(a[gid], sc, sh);
    if (addres) v += xres[gid];
    o[gid] = fmaxf(v, 0.0f);
}

// ---------------- launcher ----------------

extern "C" void kernel_launch(void* const* d_in, const int* in_sizes, int n_in,
                              void* d_out, int out_size, void* d_ws, size_t ws_size,
                              hipStream_t stream) {
    const float* x   = (const float*)d_in[0];
    const int*   ei  = (const int*)d_in[1];
    const float* W1  = (const float*)d_in[2];
    const float* b1  = (const float*)d_in[3];
    const float* g1  = (const float*)d_in[4];
    const float* be1 = (const float*)d_in[5];
    const float* W2  = (const float*)d_in[6];
    const float* b2  = (const float*)d_in[7];
    const float* g2  = (const float*)d_in[8];
    const float* be2 = (const float*)d_in[9];
    const float* W3  = (const float*)d_in[10];
    const float* b3  = (const float*)d_in[11];
    float* out = (float*)d_out;

    const int* src = ei;
    const int* dst = ei + EE;

    // workspace carve-up (256B aligned)
    char* w = (char*)d_ws;
    size_t off = 0;
    auto alloc = [&](size_t bytes) {
        void* p = w + off;
        off += (bytes + 255) & ~(size_t)255;
        return p;
    };
    float* dinv      = (float*)alloc((size_t)NN * 4);       // deg -> dinv in place
    int*   counts    = (int*)alloc((size_t)NN * 4);         // counts -> inclusive scan in place
    int*   row_ptr   = (int*)alloc((size_t)(NN + 1) * 4);
    int*   cursor    = (int*)alloc((size_t)NN * 4);
    int*   blocksums = (int*)alloc(256 * 4);
    int*   csr_src   = (int*)alloc((size_t)EE * 4);
    float* csr_coef  = (float*)alloc((size_t)EE * 4);
    float* stats     = (float*)alloc(256 * 4);
    float* hA        = (float*)alloc((size_t)NN * 128 * 4);
    float* hB        = (float*)alloc((size_t)NN * 128 * 4);

    const int NB_N   = (NN + 255) / 256;      // 391
    const int NB_E   = (EE + 255) / 256;      // 6250
    const int NSB    = (NN + 1023) / 1024;    // 98

    // ---- graph preprocessing ----
    init_deg_counts<<<NB_N, 256, 0, stream>>>(dinv, counts, NN);
    edge_count<<<NB_E, 256, 0, stream>>>(dst, dinv, counts, EE);
    make_dinv<<<NB_N, 256, 0, stream>>>(dinv, NN);
    scan1<<<NSB, 1024, 0, stream>>>(counts, blocksums, NN);
    scan2<<<1, 128, 0, stream>>>(blocksums, NSB);
    scan3<<<NB_N, 256, 0, stream>>>(counts, blocksums, row_ptr, cursor, NN);
    fill_csr<<<NB_E, 256, 0, stream>>>(src, dst, dinv, cursor, csr_src, csr_coef, EE);

    // ---- layer 1 ----
    gemm128<<<NN / 32, 256, 0, stream>>>(x, W1, hA);
    agg128<<<NN, 128, 0, stream>>>(hA, row_ptr, csr_src, csr_coef, dinv, b1, hB);
    zero_stats<<<1, 256, 0, stream>>>(stats);
    bn_stats<<<512, 128, 0, stream>>>(hB, stats, NN);
    bn_apply<<<(NN * 128 + 255) / 256, 256, 0, stream>>>(hB, x, g1, be1, stats, hA, NN, 1);

    // ---- layer 2 ----
    gemm128<<<NN / 32, 256, 0, stream>>>(hA, W2, hB);
    agg128<<<NN, 128, 0, stream>>>(hB, row_ptr, csr_src, csr_coef, dinv, b2, hA);
    zero_stats<<<1, 256, 0, stream>>>(stats);
    bn_stats<<<512, 128, 0, stream>>>(hA, stats, NN);
    bn_apply<<<(NN * 128 + 255) / 256, 256, 0, stream>>>(hA, (const float*)nullptr, g2, be2, stats, hB, NN, 0);

    // ---- layer 3 ----
    gemm40<<<(NN + 255) / 256, 256, 0, stream>>>(hB, W3, hA, NN);
    agg40_lsm<<<(NN + 3) / 4, 256, 0, stream>>>(hA, row_ptr, csr_src, csr_coef, dinv, b3, out, NN);
}

// Round 2
// 730.278 us; speedup vs baseline: 1.4753x; 1.4753x over previous
//
#include <hip/hip_runtime.h>
#include <hip/hip_bf16.h>

#define NN 100000
#define EE 1600000
#define HID 128
#define CLS 40
#define EPSBN 1e-5f

static __device__ __forceinline__ unsigned short f2bf(float f) {
    unsigned u = __float_as_uint(f);
    unsigned r = (u + 0x7fff + ((u >> 16) & 1)) >> 16;   // RNE
    return (unsigned short)r;
}
static __device__ __forceinline__ unsigned pack2(float a, float b) {
    return (unsigned)f2bf(a) | ((unsigned)f2bf(b) << 16);
}
static __device__ __forceinline__ float bflo(unsigned v) { return __uint_as_float(v << 16); }
static __device__ __forceinline__ float bfhi(unsigned v) { return __uint_as_float(v & 0xffff0000u); }

// ---------------- degree / CSR build ----------------

__global__ void init_counts(int* counts, int n) {
    int i = blockIdx.x * 256 + threadIdx.x;
    if (i < n) counts[i] = 0;
}

__global__ void edge_count(const int* __restrict__ dst, int* counts, int e) {
    int i = blockIdx.x * 256 + threadIdx.x;
    if (i < e) atomicAdd(&counts[dst[i]], 1);
}

__global__ void make_dinv(const int* __restrict__ counts, float* dinv, int n) {
    int i = blockIdx.x * 256 + threadIdx.x;
    if (i < n) dinv[i] = rsqrtf((float)(counts[i] + 1));   // +1 self loop
}

__global__ __launch_bounds__(1024) void scan1(int* counts, int* blocksums, int n) {
    __shared__ int tmp[1024];
    int tid = threadIdx.x;
    int gid = blockIdx.x * 1024 + tid;
    int v = (gid < n) ? counts[gid] : 0;
    tmp[tid] = v;
    __syncthreads();
    for (int off = 1; off < 1024; off <<= 1) {
        int t = (tid >= off) ? tmp[tid - off] : 0;
        __syncthreads();
        tmp[tid] += t;
        __syncthreads();
    }
    if (gid < n) counts[gid] = tmp[tid];
    if (tid == 1023) blocksums[blockIdx.x] = tmp[1023];
}

__global__ void scan2(int* blocksums, int nb) {
    __shared__ int tmp[128];
    int tid = threadIdx.x;
    int v = (tid < nb) ? blocksums[tid] : 0;
    tmp[tid] = v;
    __syncthreads();
    for (int off = 1; off < 128; off <<= 1) {
        int t = (tid >= off) ? tmp[tid - off] : 0;
        __syncthreads();
        tmp[tid] += t;
        __syncthreads();
    }
    if (tid < nb) blocksums[tid] = (tid == 0) ? 0 : tmp[tid - 1];
}

__global__ void scan3(const int* __restrict__ incl, const int* __restrict__ blocksums,
                      int* row_ptr, int* cursor, int n) {
    int gid = blockIdx.x * 256 + threadIdx.x;
    if (gid >= n) return;
    int inc = incl[gid] + blocksums[gid >> 10];
    row_ptr[gid + 1] = inc;
    int start = (gid == 0) ? 0 : incl[gid - 1] + blocksums[(gid - 1) >> 10];
    cursor[gid] = start;
    if (gid == 0) row_ptr[0] = 0;
}

__global__ void fill_csr(const int* __restrict__ src, const int* __restrict__ dst,
                         const float* __restrict__ dinv, int* cursor,
                         int2* __restrict__ csr, int e) {
    int i = blockIdx.x * 256 + threadIdx.x;
    if (i >= e) return;
    int s = src[i], d = dst[i];
    int p = atomicAdd(&cursor[d], 1);
    csr[p] = make_int2(s, __float_as_int(dinv[s] * dinv[d]));
}

// ---------------- GEMMs ----------------

// MODE 0: plain X. MODE 1: X := relu(bn(X) + xres).  Out = bf16-packed H.
template <int MODE>
__global__ __launch_bounds__(256) void gemm128_t(const float* __restrict__ X,
                                                 const float* __restrict__ W,
                                                 const float* __restrict__ scsh,
                                                 const float* __restrict__ xres,
                                                 unsigned* __restrict__ Hb) {
    __shared__ float ws[128][128];
    __shared__ float xs[32][128];
    __shared__ float ss[256];           // sc[128], sh[128]
    int t = threadIdx.x;
    {
        const float4* Wv = (const float4*)W;
        float4* wsv = (float4*)&ws[0][0];
        for (int i = t; i < 128 * 32; i += 256) wsv[i] = Wv[i];
    }
    if (MODE == 1 && t < 64) ((float4*)ss)[t] = ((const float4*)scsh)[t];
    __syncthreads();
    int row0 = blockIdx.x * 32;
    {
        const float4* Xv = (const float4*)(X + (size_t)row0 * 128);
        const float4* Rv = (const float4*)(xres + (size_t)row0 * 128);
        float4* xsv = (float4*)&xs[0][0];
        for (int i = t; i < 32 * 32; i += 256) {
            float4 a = Xv[i];
            if (MODE == 1) {
                int c0 = (i & 31) * 4;
                float4 r = Rv[i];
                a.x = fmaxf(fmaf(a.x, ss[c0 + 0], ss[128 + c0 + 0]) + r.x, 0.0f);
                a.y = fmaxf(fmaf(a.y, ss[c0 + 1], ss[128 + c0 + 1]) + r.y, 0.0f);
                a.z = fmaxf(fmaf(a.z, ss[c0 + 2], ss[128 + c0 + 2]) + r.z, 0.0f);
                a.w = fmaxf(fmaf(a.w, ss[c0 + 3], ss[128 + c0 + 3]) + r.w, 0.0f);
            }
            xsv[i] = a;
        }
    }
    __syncthreads();
    int tj = t & 31;
    int ti = t >> 5;
    float acc[4][4] = {};
    for (int k = 0; k < 128; k += 4) {
        float4 xa[4], wb[4];
#pragma unroll
        for (int r = 0; r < 4; r++) xa[r] = *(const float4*)&xs[4 * ti + r][k];
#pragma unroll
        for (int kk = 0; kk < 4; kk++) wb[kk] = *(const float4*)&ws[k + kk][4 * tj];
#pragma unroll
        for (int kk = 0; kk < 4; kk++) {
#pragma unroll
            for (int r = 0; r < 4; r++) {
                float xv = ((const float*)&xa[r])[kk];
                acc[r][0] = fmaf(xv, wb[kk].x, acc[r][0]);
                acc[r][1] = fmaf(xv, wb[kk].y, acc[r][1]);
                acc[r][2] = fmaf(xv, wb[kk].z, acc[r][2]);
                acc[r][3] = fmaf(xv, wb[kk].w, acc[r][3]);
            }
        }
    }
#pragma unroll
    for (int r = 0; r < 4; r++) {
        uint2 o;
        o.x = pack2(acc[r][0], acc[r][1]);
        o.y = pack2(acc[r][2], acc[r][3]);
        *(uint2*)&Hb[(size_t)(row0 + 4 * ti + r) * 64 + tj * 2] = o;
    }
}

// layer-3 GEMM: X := relu(bn(A)), W3[128 x 40], out bf16 [N][40]
__global__ __launch_bounds__(256) void gemm40_bn(const float* __restrict__ A,
                                                 const float* __restrict__ W3,
                                                 const float* __restrict__ scsh,
                                                 unsigned* __restrict__ H3, int n) {
    __shared__ float ws[128][CLS];
    __shared__ float ss[256];
    int t = threadIdx.x;
    for (int i = t; i < 128 * CLS; i += 256) ws[i / CLS][i % CLS] = W3[i];
    if (t < 64) ((float4*)ss)[t] = ((const float4*)scsh)[t];
    __syncthreads();
    int row = blockIdx.x * 256 + t;
    if (row >= n) return;
    const float4* xr = (const float4*)(A + (size_t)row * 128);
    float acc[CLS] = {};
    for (int kc = 0; kc < 32; kc++) {
        float4 xv = xr[kc];
#pragma unroll
        for (int kk = 0; kk < 4; kk++) {
            int k = kc * 4 + kk;
            float x1 = fmaxf(fmaf(((const float*)&xv)[kk], ss[k], ss[128 + k]), 0.0f);
#pragma unroll
            for (int j = 0; j < CLS; j++) acc[j] = fmaf(x1, ws[k][j], acc[j]);
        }
    }
    uint2* o = (uint2*)&H3[(size_t)row * 20];
#pragma unroll
    for (int j = 0; j < 10; j++)
        o[j] = make_uint2(pack2(acc[4 * j], acc[4 * j + 1]), pack2(acc[4 * j + 2], acc[4 * j + 3]));
}

// ---------------- aggregation ----------------

// bf16 gather: one wave per node, lane handles features (2l, 2l+1). Out fp32 + bias.
__global__ __launch_bounds__(256) void agg128_bf16(const unsigned* __restrict__ h,
                                                   const int* __restrict__ row_ptr,
                                                   const int2* __restrict__ csr,
                                                   const float* __restrict__ dinv,
                                                   const float* __restrict__ bias,
                                                   float* __restrict__ out) {
    int wid = threadIdx.x >> 6;
    int lane = threadIdx.x & 63;
    int node = blockIdx.x * 4 + wid;
    float di = dinv[node];
    float c0 = di * di;
    unsigned v = h[node * 64 + lane];
    float a0 = bflo(v) * c0;
    float a1 = bfhi(v) * c0;
    int beg = row_ptr[node], end = row_ptr[node + 1];
    int e = beg;
    for (; e + 4 <= end; e += 4) {
        int2 p0 = csr[e], p1 = csr[e + 1], p2 = csr[e + 2], p3 = csr[e + 3];
        unsigned h0 = h[p0.x * 64 + lane];
        unsigned h1 = h[p1.x * 64 + lane];
        unsigned h2 = h[p2.x * 64 + lane];
        unsigned h3 = h[p3.x * 64 + lane];
        float q0 = __int_as_float(p0.y), q1 = __int_as_float(p1.y);
        float q2 = __int_as_float(p2.y), q3 = __int_as_float(p3.y);
        a0 = fmaf(bflo(h0), q0, a0); a1 = fmaf(bfhi(h0), q0, a1);
        a0 = fmaf(bflo(h1), q1, a0); a1 = fmaf(bfhi(h1), q1, a1);
        a0 = fmaf(bflo(h2), q2, a0); a1 = fmaf(bfhi(h2), q2, a1);
        a0 = fmaf(bflo(h3), q3, a0); a1 = fmaf(bfhi(h3), q3, a1);
    }
    for (; e < end; ++e) {
        int2 p = csr[e];
        float q = __int_as_float(p.y);
        unsigned hv = h[p.x * 64 + lane];
        a0 = fmaf(bflo(hv), q, a0);
        a1 = fmaf(bfhi(hv), q, a1);
    }
    float2 b = *(const float2*)&bias[lane * 2];
    *(float2*)&out[(size_t)node * 128 + lane * 2] = make_float2(a0 + b.x, a1 + b.y);
}

// layer-3 aggregation (bf16 rows of 20 uints) fused with bias + log_softmax
__global__ __launch_bounds__(256) void agg40_lsm(const unsigned* __restrict__ h3,
                                                 const int* __restrict__ row_ptr,
                                                 const int2* __restrict__ csr,
                                                 const float* __restrict__ dinv,
                                                 const float* __restrict__ b3,
                                                 float* __restrict__ out) {
    int wid = threadIdx.x >> 6;
    int lane = threadIdx.x & 63;
    int node = blockIdx.x * 4 + wid;
    bool act = lane < 20;
    float di = dinv[node];
    float c0 = di * di;
    unsigned v = act ? h3[node * 20 + lane] : 0u;
    float a0 = bflo(v) * c0;
    float a1 = bfhi(v) * c0;
    int beg = row_ptr[node], end = row_ptr[node + 1];
    int e = beg;
    for (; e + 4 <= end; e += 4) {
        int2 p0 = csr[e], p1 = csr[e + 1], p2 = csr[e + 2], p3 = csr[e + 3];
        unsigned h0 = 0, h1 = 0, h2 = 0, h3v = 0;
        if (act) {
            h0 = h3[p0.x * 20 + lane];
            h1 = h3[p1.x * 20 + lane];
            h2 = h3[p2.x * 20 + lane];
            h3v = h3[p3.x * 20 + lane];
        }
        float q0 = __int_as_float(p0.y), q1 = __int_as_float(p1.y);
        float q2 = __int_as_float(p2.y), q3 = __int_as_float(p3.y);
        a0 = fmaf(bflo(h0), q0, a0); a1 = fmaf(bfhi(h0), q0, a1);
        a0 = fmaf(bflo(h1), q1, a0); a1 = fmaf(bfhi(h1), q1, a1);
        a0 = fmaf(bflo(h2), q2, a0); a1 = fmaf(bfhi(h2), q2, a1);
        a0 = fmaf(bflo(h3v), q3, a0); a1 = fmaf(bfhi(h3v), q3, a1);
    }
    for (; e < end; ++e) {
        int2 p = csr[e];
        float q = __int_as_float(p.y);
        unsigned hv = act ? h3[p.x * 20 + lane] : 0u;
        a0 = fmaf(bflo(hv), q, a0);
        a1 = fmaf(bfhi(hv), q, a1);
    }
    float l0 = a0, l1 = a1;
    if (act) {
        float2 b = *(const float2*)&b3[lane * 2];
        l0 += b.x;
        l1 += b.y;
    }
    float m = act ? fmaxf(l0, l1) : -1e30f;
#pragma unroll
    for (int off = 32; off > 0; off >>= 1) m = fmaxf(m, __shfl_xor(m, off));
    float s = act ? (expf(l0 - m) + expf(l1 - m)) : 0.0f;
#pragma unroll
    for (int off = 32; off > 0; off >>= 1) s += __shfl_xor(s, off);
    float lse = m + logf(s);
    if (act) *(float2*)&out[(size_t)node * CLS + lane * 2] = make_float2(l0 - lse, l1 - lse);
}

// ---------------- batchnorm stats ----------------

__global__ void zero_stats(float* stats) {
    if (threadIdx.x < 256) stats[threadIdx.x] = 0.0f;
}

__global__ __launch_bounds__(128) void bn_stats(const float* __restrict__ a,
                                                float* __restrict__ stats, int n) {
    int f = threadIdx.x;
    float s = 0.0f, s2 = 0.0f;
    for (int i = blockIdx.x; i < n; i += gridDim.x) {
        float v = a[(size_t)i * 128 + f];
        s += v;
        s2 = fmaf(v, v, s2);
    }
    atomicAdd(&stats[f], s);
    atomicAdd(&stats[128 + f], s2);
}

__global__ void finalize_scsh(const float* __restrict__ stats, const float* __restrict__ g,
                              const float* __restrict__ be, float* __restrict__ scsh) {
    int f = threadIdx.x;   // 128 threads
    float mean = stats[f] * (1.0f / (float)NN);
    float var = stats[128 + f] * (1.0f / (float)NN) - mean * mean;
    float sc = g[f] * rsqrtf(var + EPSBN);
    scsh[f] = sc;
    scsh[128 + f] = be[f] - mean * sc;
}

// ---------------- launcher ----------------

extern "C" void kernel_launch(void* const* d_in, const int* in_sizes, int n_in,
                              void* d_out, int out_size, void* d_ws, size_t ws_size,
                              hipStream_t stream) {
    const float* x   = (const float*)d_in[0];
    const int*   ei  = (const int*)d_in[1];
    const float* W1  = (const float*)d_in[2];
    const float* b1  = (const float*)d_in[3];
    const float* g1  = (const float*)d_in[4];
    const float* be1 = (const float*)d_in[5];
    const float* W2  = (const float*)d_in[6];
    const float* b2  = (const float*)d_in[7];
    const float* g2  = (const float*)d_in[8];
    const float* be2 = (const float*)d_in[9];
    const float* W3  = (const float*)d_in[10];
    const float* b3  = (const float*)d_in[11];
    float* out = (float*)d_out;

    const int* src = ei;
    const int* dst = ei + EE;

    char* w = (char*)d_ws;
    size_t off = 0;
    auto alloc = [&](size_t bytes) {
        void* p = w + off;
        off += (bytes + 255) & ~(size_t)255;
        return p;
    };
    float* dinv      = (float*)alloc((size_t)NN * 4);
    int*   counts    = (int*)alloc((size_t)NN * 4);
    int*   row_ptr   = (int*)alloc((size_t)(NN + 1) * 4);
    int*   cursor    = (int*)alloc((size_t)NN * 4);
    int*   blocksums = (int*)alloc(256 * 4);
    int2*  csr       = (int2*)alloc((size_t)EE * 8);
    float* stats     = (float*)alloc(256 * 4);
    float* scsh      = (float*)alloc(256 * 4);
    float* aF        = (float*)alloc((size_t)NN * 128 * 4);   // fp32 agg output
    unsigned* hB     = (unsigned*)alloc((size_t)NN * 64 * 4); // bf16 h (pairs)
    unsigned* h3     = (unsigned*)alloc((size_t)NN * 20 * 4); // bf16 h3 (pairs)

    const int NB_N = (NN + 255) / 256;
    const int NB_E = (EE + 255) / 256;
    const int NSB  = (NN + 1023) / 1024;

    // ---- graph preprocessing ----
    init_counts<<<NB_N, 256, 0, stream>>>(counts, NN);
    edge_count<<<NB_E, 256, 0, stream>>>(dst, counts, EE);
    make_dinv<<<NB_N, 256, 0, stream>>>(counts, dinv, NN);
    scan1<<<NSB, 1024, 0, stream>>>(counts, blocksums, NN);
    scan2<<<1, 128, 0, stream>>>(blocksums, NSB);
    scan3<<<NB_N, 256, 0, stream>>>(counts, blocksums, row_ptr, cursor, NN);
    fill_csr<<<NB_E, 256, 0, stream>>>(src, dst, dinv, cursor, csr, EE);

    // ---- layer 1 ----
    gemm128_t<0><<<NN / 32, 256, 0, stream>>>(x, W1, nullptr, nullptr, hB);
    agg128_bf16<<<NN / 4, 256, 0, stream>>>(hB, row_ptr, csr, dinv, b1, aF);
    zero_stats<<<1, 256, 0, stream>>>(stats);
    bn_stats<<<512, 128, 0, stream>>>(aF, stats, NN);
    finalize_scsh<<<1, 128, 0, stream>>>(stats, g1, be1, scsh);

    // ---- layer 2 (BN1 + residual + relu fused into GEMM staging) ----
    gemm128_t<1><<<NN / 32, 256, 0, stream>>>(aF, W2, scsh, x, hB);
    agg128_bf16<<<NN / 4, 256, 0, stream>>>(hB, row_ptr, csr, dinv, b2, aF);
    zero_stats<<<1, 256, 0, stream>>>(stats);
    bn_stats<<<512, 128, 0, stream>>>(aF, stats, NN);
    finalize_scsh<<<1, 128, 0, stream>>>(stats, g2, be2, scsh);

    // ---- layer 3 (BN2 + relu fused into GEMM) ----
    gemm40_bn<<<(NN + 255) / 256, 256, 0, stream>>>(aF, W3, scsh, h3, NN);
    agg40_lsm<<<NN / 4, 256, 0, stream>>>(h3, row_ptr, csr, dinv, b3, out);
}

// Round 3
// 585.866 us; speedup vs baseline: 1.8390x; 1.2465x over previous
//
#include <hip/hip_runtime.h>
#include <hip/hip_bf16.h>

#define NN 100000
#define EE 1600000
#define HID 128
#define CLS 40
#define EPSBN 1e-5f

typedef float f32x4 __attribute__((ext_vector_type(4)));
typedef short s16x8 __attribute__((ext_vector_type(8)));
union U48 { uint4 u; s16x8 s; };

static __device__ __forceinline__ unsigned short f2bf(float f) {
    unsigned u = __float_as_uint(f);
    unsigned r = (u + 0x7fff + ((u >> 16) & 1)) >> 16;   // RNE
    return (unsigned short)r;
}
static __device__ __forceinline__ unsigned pack2(float a, float b) {
    return (unsigned)f2bf(a) | ((unsigned)f2bf(b) << 16);
}
static __device__ __forceinline__ float bflo(unsigned v) { return __uint_as_float(v << 16); }
static __device__ __forceinline__ float bfhi(unsigned v) { return __uint_as_float(v & 0xffff0000u); }

// ---------------- degree / CSR build ----------------

__global__ void init_counts(int* counts, int n) {
    int i = blockIdx.x * 256 + threadIdx.x;
    if (i < n) counts[i] = 0;
}

__global__ void edge_count(const int* __restrict__ dst, int* counts, int e) {
    int i = blockIdx.x * 256 + threadIdx.x;
    if (i < e) atomicAdd(&counts[dst[i]], 1);
}

__global__ void make_dinv(const int* __restrict__ counts, float* dinv, int n) {
    int i = blockIdx.x * 256 + threadIdx.x;
    if (i < n) dinv[i] = rsqrtf((float)(counts[i] + 1));   // +1 self loop
}

__global__ __launch_bounds__(1024) void scan1(int* counts, int* blocksums, int n) {
    __shared__ int tmp[1024];
    int tid = threadIdx.x;
    int gid = blockIdx.x * 1024 + tid;
    int v = (gid < n) ? counts[gid] : 0;
    tmp[tid] = v;
    __syncthreads();
    for (int off = 1; off < 1024; off <<= 1) {
        int t = (tid >= off) ? tmp[tid - off] : 0;
        __syncthreads();
        tmp[tid] += t;
        __syncthreads();
    }
    if (gid < n) counts[gid] = tmp[tid];
    if (tid == 1023) blocksums[blockIdx.x] = tmp[1023];
}

__global__ void scan2(int* blocksums, int nb) {
    __shared__ int tmp[128];
    int tid = threadIdx.x;
    int v = (tid < nb) ? blocksums[tid] : 0;
    tmp[tid] = v;
    __syncthreads();
    for (int off = 1; off < 128; off <<= 1) {
        int t = (tid >= off) ? tmp[tid - off] : 0;
        __syncthreads();
        tmp[tid] += t;
        __syncthreads();
    }
    if (tid < nb) blocksums[tid] = (tid == 0) ? 0 : tmp[tid - 1];
}

__global__ void scan3(const int* __restrict__ incl, const int* __restrict__ blocksums,
                      int* row_ptr, int* cursor, int n) {
    int gid = blockIdx.x * 256 + threadIdx.x;
    if (gid >= n) return;
    int inc = incl[gid] + blocksums[gid >> 10];
    row_ptr[gid + 1] = inc;
    int start = (gid == 0) ? 0 : incl[gid - 1] + blocksums[(gid - 1) >> 10];
    cursor[gid] = start;
    if (gid == 0) row_ptr[0] = 0;
}

__global__ void fill_csr(const int* __restrict__ src, const int* __restrict__ dst,
                         const float* __restrict__ dinv, int* cursor,
                         int2* __restrict__ csr, int e) {
    int i = blockIdx.x * 256 + threadIdx.x;
    if (i >= e) return;
    int s = src[i], d = dst[i];
    int p = atomicAdd(&cursor[d], 1);
    csr[p] = make_int2(s, __float_as_int(dinv[s] * dinv[d]));
}

// ---------------- W pre-pack into MFMA B-fragment layout ----------------
// 128-col W: frag f = ks*8 + ct (ks<4, ct<8); lane holds col=ct*16+(l&15),
// k = ks*32+(l>>4)*8+j (j=0..7, bf16 pairs per uint). 8192 uints.
__global__ void prep_w128(const float* __restrict__ W, unsigned* __restrict__ Wf) {
    int t = blockIdx.x * 256 + threadIdx.x;   // < 8192
    int q = t & 3, lane = (t >> 2) & 63, f = t >> 8;
    int ks = f >> 3, ct = f & 7;
    int k = ks * 32 + ((lane >> 4) << 3) + q * 2;
    int col = ct * 16 + (lane & 15);
    Wf[t] = pack2(W[k * 128 + col], W[(k + 1) * 128 + col]);
}

// 40-col W3 padded to 48: frag f = ks*3 + ct (ks<4, ct<3). 3072 uints.
__global__ void prep_w40(const float* __restrict__ W, unsigned* __restrict__ Wf) {
    int t = blockIdx.x * 256 + threadIdx.x;   // < 3072
    int q = t & 3, lane = (t >> 2) & 63, f = t >> 8;
    int ks = f / 3, ct = f - ks * 3;
    int k = ks * 32 + ((lane >> 4) << 3) + q * 2;
    int col = ct * 16 + (lane & 15);
    float v0 = (col < CLS) ? W[k * CLS + col] : 0.0f;
    float v1 = (col < CLS) ? W[(k + 1) * CLS + col] : 0.0f;
    Wf[t] = pack2(v0, v1);
}

// ---------------- MFMA GEMMs ----------------

// MODE 0: A = X.  MODE 1: A = relu(bn(X) + xres).  Out: bf16-packed H [N][128].
// Block: 64 rows x 128 cols, 4 waves (2x2). Wave: 32 rows x 64 cols, 32 MFMAs.
template <int MODE>
__global__ __launch_bounds__(256) void gemm128_mfma(const float* __restrict__ X,
                                                    const unsigned* __restrict__ Wf,
                                                    const float* __restrict__ scsh,
                                                    const float* __restrict__ xres,
                                                    unsigned* __restrict__ Hb) {
    int t = threadIdx.x;
    int lane = t & 63, w = t >> 6;
    int wr = w >> 1, wc = w & 1;
    int row_base = blockIdx.x * 64 + wr * 32;

    // B fragments: register-resident W
    s16x8 b[4][4];
    const uint4* Wv = (const uint4*)Wf;
#pragma unroll
    for (int ks = 0; ks < 4; ks++)
#pragma unroll
        for (int ct = 0; ct < 4; ct++) {
            int f = ks * 8 + wc * 4 + ct;
            U48 u; u.u = Wv[f * 64 + lane];
            b[ks][ct] = u.s;
        }

    f32x4 acc[2][4] = {};
    int lrow = lane & 15;
    int koff = (lane >> 4) << 3;

#pragma unroll
    for (int ks = 0; ks < 4; ks++) {
        int k0 = ks * 32 + koff;
        float sc[8], sh[8];
        if (MODE == 1) {
            float4 s0 = *(const float4*)&scsh[k0];
            float4 s1 = *(const float4*)&scsh[k0 + 4];
            float4 h0 = *(const float4*)&scsh[128 + k0];
            float4 h1 = *(const float4*)&scsh[128 + k0 + 4];
            sc[0]=s0.x; sc[1]=s0.y; sc[2]=s0.z; sc[3]=s0.w;
            sc[4]=s1.x; sc[5]=s1.y; sc[6]=s1.z; sc[7]=s1.w;
            sh[0]=h0.x; sh[1]=h0.y; sh[2]=h0.z; sh[3]=h0.w;
            sh[4]=h1.x; sh[5]=h1.y; sh[6]=h1.z; sh[7]=h1.w;
        }
#pragma unroll
        for (int rf = 0; rf < 2; rf++) {
            int row = row_base + rf * 16 + lrow;
            float v[8];
            if (row < NN) {
                float4 a0 = *(const float4*)&X[(size_t)row * 128 + k0];
                float4 a1 = *(const float4*)&X[(size_t)row * 128 + k0 + 4];
                v[0]=a0.x; v[1]=a0.y; v[2]=a0.z; v[3]=a0.w;
                v[4]=a1.x; v[5]=a1.y; v[6]=a1.z; v[7]=a1.w;
                if (MODE == 1) {
                    float4 r0 = *(const float4*)&xres[(size_t)row * 128 + k0];
                    float4 r1 = *(const float4*)&xres[(size_t)row * 128 + k0 + 4];
                    float rr[8] = {r0.x,r0.y,r0.z,r0.w,r1.x,r1.y,r1.z,r1.w};
#pragma unroll
                    for (int j = 0; j < 8; j++)
                        v[j] = fmaxf(fmaf(v[j], sc[j], sh[j]) + rr[j], 0.0f);
                }
            } else {
#pragma unroll
                for (int j = 0; j < 8; j++) v[j] = 0.0f;
            }
            U48 a;
            a.u = make_uint4(pack2(v[0], v[1]), pack2(v[2], v[3]),
                             pack2(v[4], v[5]), pack2(v[6], v[7]));
#pragma unroll
            for (int ct = 0; ct < 4; ct++)
                acc[rf][ct] = __builtin_amdgcn_mfma_f32_16x16x32_bf16(a.s, b[ks][ct], acc[rf][ct], 0, 0, 0);
        }
    }

    // store bf16 (C/D: col=lane&15, row=(lane>>4)*4+reg)
    unsigned short* Hs = (unsigned short*)Hb;
#pragma unroll
    for (int rf = 0; rf < 2; rf++)
#pragma unroll
        for (int ct = 0; ct < 4; ct++) {
            int col = wc * 64 + ct * 16 + lrow;
            int rbase = row_base + rf * 16 + ((lane >> 4) << 2);
#pragma unroll
            for (int r = 0; r < 4; r++) {
                int row = rbase + r;
                if (row < NN) Hs[(size_t)row * 128 + col] = f2bf(acc[rf][ct][r]);
            }
        }
}

// layer-3: A = relu(bn(X)), W3 frags (48 cols, last 8 dead). Out bf16 [N][40].
__global__ __launch_bounds__(256) void gemm40_mfma(const float* __restrict__ X,
                                                   const unsigned* __restrict__ Wf,
                                                   const float* __restrict__ scsh,
                                                   unsigned* __restrict__ H3) {
    int t = threadIdx.x;
    int lane = t & 63, w = t >> 6;
    int row_base = blockIdx.x * 64 + w * 16;

    s16x8 b[4][3];
    const uint4* Wv = (const uint4*)Wf;
#pragma unroll
    for (int ks = 0; ks < 4; ks++)
#pragma unroll
        for (int ct = 0; ct < 3; ct++) {
            U48 u; u.u = Wv[(ks * 3 + ct) * 64 + lane];
            b[ks][ct] = u.s;
        }

    f32x4 acc[3] = {};
    int lrow = lane & 15;
    int koff = (lane >> 4) << 3;

#pragma unroll
    for (int ks = 0; ks < 4; ks++) {
        int k0 = ks * 32 + koff;
        float4 s0 = *(const float4*)&scsh[k0];
        float4 s1 = *(const float4*)&scsh[k0 + 4];
        float4 h0 = *(const float4*)&scsh[128 + k0];
        float4 h1 = *(const float4*)&scsh[128 + k0 + 4];
        float sc[8] = {s0.x,s0.y,s0.z,s0.w,s1.x,s1.y,s1.z,s1.w};
        float sh[8] = {h0.x,h0.y,h0.z,h0.w,h1.x,h1.y,h1.z,h1.w};
        int row = row_base + lrow;
        float v[8];
        if (row < NN) {
            float4 a0 = *(const float4*)&X[(size_t)row * 128 + k0];
            float4 a1 = *(const float4*)&X[(size_t)row * 128 + k0 + 4];
            float av[8] = {a0.x,a0.y,a0.z,a0.w,a1.x,a1.y,a1.z,a1.w};
#pragma unroll
            for (int j = 0; j < 8; j++)
                v[j] = fmaxf(fmaf(av[j], sc[j], sh[j]), 0.0f);
        } else {
#pragma unroll
            for (int j = 0; j < 8; j++) v[j] = 0.0f;
        }
        U48 a;
        a.u = make_uint4(pack2(v[0], v[1]), pack2(v[2], v[3]),
                         pack2(v[4], v[5]), pack2(v[6], v[7]));
#pragma unroll
        for (int ct = 0; ct < 3; ct++)
            acc[ct] = __builtin_amdgcn_mfma_f32_16x16x32_bf16(a.s, b[ks][ct], acc[ct], 0, 0, 0);
    }

    unsigned short* Hs = (unsigned short*)H3;
#pragma unroll
    for (int ct = 0; ct < 3; ct++) {
        int col = ct * 16 + lrow;
        if (col >= CLS) continue;
        int rbase = row_base + ((lane >> 4) << 2);
#pragma unroll
        for (int r = 0; r < 4; r++) {
            int row = rbase + r;
            if (row < NN) Hs[(size_t)row * CLS + col] = f2bf(acc[ct][r]);
        }
    }
}

// ---------------- aggregation ----------------

__global__ __launch_bounds__(256) void agg128_bf16(const unsigned* __restrict__ h,
                                                   const int* __restrict__ row_ptr,
                                                   const int2* __restrict__ csr,
                                                   const float* __restrict__ dinv,
                                                   const float* __restrict__ bias,
                                                   float* __restrict__ out) {
    int wid = threadIdx.x >> 6;
    int lane = threadIdx.x & 63;
    int node = blockIdx.x * 4 + wid;
    float di = dinv[node];
    float c0 = di * di;
    unsigned v = h[node * 64 + lane];
    float a0 = bflo(v) * c0;
    float a1 = bfhi(v) * c0;
    int beg = row_ptr[node], end = row_ptr[node + 1];
    int e = beg;
    for (; e + 4 <= end; e += 4) {
        int2 p0 = csr[e], p1 = csr[e + 1], p2 = csr[e + 2], p3 = csr[e + 3];
        unsigned h0 = h[p0.x * 64 + lane];
        unsigned h1 = h[p1.x * 64 + lane];
        unsigned h2 = h[p2.x * 64 + lane];
        unsigned h3 = h[p3.x * 64 + lane];
        float q0 = __int_as_float(p0.y), q1 = __int_as_float(p1.y);
        float q2 = __int_as_float(p2.y), q3 = __int_as_float(p3.y);
        a0 = fmaf(bflo(h0), q0, a0); a1 = fmaf(bfhi(h0), q0, a1);
        a0 = fmaf(bflo(h1), q1, a0); a1 = fmaf(bfhi(h1), q1, a1);
        a0 = fmaf(bflo(h2), q2, a0); a1 = fmaf(bfhi(h2), q2, a1);
        a0 = fmaf(bflo(h3), q3, a0); a1 = fmaf(bfhi(h3), q3, a1);
    }
    for (; e < end; ++e) {
        int2 p = csr[e];
        float q = __int_as_float(p.y);
        unsigned hv = h[p.x * 64 + lane];
        a0 = fmaf(bflo(hv), q, a0);
        a1 = fmaf(bfhi(hv), q, a1);
    }
    float2 b = *(const float2*)&bias[lane * 2];
    *(float2*)&out[(size_t)node * 128 + lane * 2] = make_float2(a0 + b.x, a1 + b.y);
}

__global__ __launch_bounds__(256) void agg40_lsm(const unsigned* __restrict__ h3,
                                                 const int* __restrict__ row_ptr,
                                                 const int2* __restrict__ csr,
                                                 const float* __restrict__ dinv,
                                                 const float* __restrict__ b3,
                                                 float* __restrict__ out) {
    int wid = threadIdx.x >> 6;
    int lane = threadIdx.x & 63;
    int node = blockIdx.x * 4 + wid;
    bool act = lane < 20;
    float di = dinv[node];
    float c0 = di * di;
    unsigned v = act ? h3[node * 20 + lane] : 0u;
    float a0 = bflo(v) * c0;
    float a1 = bfhi(v) * c0;
    int beg = row_ptr[node], end = row_ptr[node + 1];
    int e = beg;
    for (; e + 4 <= end; e += 4) {
        int2 p0 = csr[e], p1 = csr[e + 1], p2 = csr[e + 2], p3 = csr[e + 3];
        unsigned h0 = 0, h1 = 0, h2 = 0, h3v = 0;
        if (act) {
            h0 = h3[p0.x * 20 + lane];
            h1 = h3[p1.x * 20 + lane];
            h2 = h3[p2.x * 20 + lane];
            h3v = h3[p3.x * 20 + lane];
        }
        float q0 = __int_as_float(p0.y), q1 = __int_as_float(p1.y);
        float q2 = __int_as_float(p2.y), q3 = __int_as_float(p3.y);
        a0 = fmaf(bflo(h0), q0, a0); a1 = fmaf(bfhi(h0), q0, a1);
        a0 = fmaf(bflo(h1), q1, a0); a1 = fmaf(bfhi(h1), q1, a1);
        a0 = fmaf(bflo(h2), q2, a0); a1 = fmaf(bfhi(h2), q2, a1);
        a0 = fmaf(bflo(h3v), q3, a0); a1 = fmaf(bfhi(h3v), q3, a1);
    }
    for (; e < end; ++e) {
        int2 p = csr[e];
        float q = __int_as_float(p.y);
        unsigned hv = act ? h3[p.x * 20 + lane] : 0u;
        a0 = fmaf(bflo(hv), q, a0);
        a1 = fmaf(bfhi(hv), q, a1);
    }
    float l0 = a0, l1 = a1;
    if (act) {
        float2 b = *(const float2*)&b3[lane * 2];
        l0 += b.x;
        l1 += b.y;
    }
    float m = act ? fmaxf(l0, l1) : -1e30f;
#pragma unroll
    for (int off = 32; off > 0; off >>= 1) m = fmaxf(m, __shfl_xor(m, off));
    float s = act ? (expf(l0 - m) + expf(l1 - m)) : 0.0f;
#pragma unroll
    for (int off = 32; off > 0; off >>= 1) s += __shfl_xor(s, off);
    float lse = m + logf(s);
    if (act) *(float2*)&out[(size_t)node * CLS + lane * 2] = make_float2(l0 - lse, l1 - lse);
}

// ---------------- batchnorm stats ----------------

__global__ void zero_stats(float* stats) {
    if (threadIdx.x < 256) stats[threadIdx.x] = 0.0f;
}

__global__ __launch_bounds__(128) void bn_stats(const float* __restrict__ a,
                                                float* __restrict__ stats, int n) {
    int f = threadIdx.x;
    float s = 0.0f, s2 = 0.0f;
    for (int i = blockIdx.x; i < n; i += gridDim.x) {
        float v = a[(size_t)i * 128 + f];
        s += v;
        s2 = fmaf(v, v, s2);
    }
    atomicAdd(&stats[f], s);
    atomicAdd(&stats[128 + f], s2);
}

__global__ void finalize_scsh(const float* __restrict__ stats, const float* __restrict__ g,
                              const float* __restrict__ be, float* __restrict__ scsh) {
    int f = threadIdx.x;   // 128 threads
    float mean = stats[f] * (1.0f / (float)NN);
    float var = stats[128 + f] * (1.0f / (float)NN) - mean * mean;
    float sc = g[f] * rsqrtf(var + EPSBN);
    scsh[f] = sc;
    scsh[128 + f] = be[f] - mean * sc;
}

// ---------------- launcher ----------------

extern "C" void kernel_launch(void* const* d_in, const int* in_sizes, int n_in,
                              void* d_out, int out_size, void* d_ws, size_t ws_size,
                              hipStream_t stream) {
    const float* x   = (const float*)d_in[0];
    const int*   ei  = (const int*)d_in[1];
    const float* W1  = (const float*)d_in[2];
    const float* b1  = (const float*)d_in[3];
    const float* g1  = (const float*)d_in[4];
    const float* be1 = (const float*)d_in[5];
    const float* W2  = (const float*)d_in[6];
    const float* b2  = (const float*)d_in[7];
    const float* g2  = (const float*)d_in[8];
    const float* be2 = (const float*)d_in[9];
    const float* W3  = (const float*)d_in[10];
    const float* b3  = (const float*)d_in[11];
    float* out = (float*)d_out;

    const int* src = ei;
    const int* dst = ei + EE;

    char* w = (char*)d_ws;
    size_t off = 0;
    auto alloc = [&](size_t bytes) {
        void* p = w + off;
        off += (bytes + 255) & ~(size_t)255;
        return p;
    };
    float* dinv      = (float*)alloc((size_t)NN * 4);
    int*   counts    = (int*)alloc((size_t)NN * 4);
    int*   row_ptr   = (int*)alloc((size_t)(NN + 1) * 4);
    int*   cursor    = (int*)alloc((size_t)NN * 4);
    int*   blocksums = (int*)alloc(256 * 4);
    int2*  csr       = (int2*)alloc((size_t)EE * 8);
    float* stats     = (float*)alloc(256 * 4);
    float* scsh      = (float*)alloc(256 * 4);
    unsigned* Wf1    = (unsigned*)alloc(8192 * 4);
    unsigned* Wf2    = (unsigned*)alloc(8192 * 4);
    unsigned* Wf3    = (unsigned*)alloc(3072 * 4);
    float* aF        = (float*)alloc((size_t)NN * 128 * 4);   // fp32 agg output
    unsigned* hB     = (unsigned*)alloc((size_t)NN * 64 * 4); // bf16 h (pairs)
    unsigned* h3     = (unsigned*)alloc((size_t)NN * 20 * 4); // bf16 h3 (pairs)

    const int NB_N = (NN + 255) / 256;
    const int NB_E = (EE + 255) / 256;
    const int NSB  = (NN + 1023) / 1024;
    const int NB_G = (NN + 63) / 64;    // 1563 gemm blocks

    // ---- graph preprocessing + weight prep ----
    init_counts<<<NB_N, 256, 0, stream>>>(counts, NN);
    edge_count<<<NB_E, 256, 0, stream>>>(dst, counts, EE);
    make_dinv<<<NB_N, 256, 0, stream>>>(counts, dinv, NN);
    scan1<<<NSB, 1024, 0, stream>>>(counts, blocksums, NN);
    scan2<<<1, 128, 0, stream>>>(blocksums, NSB);
    scan3<<<NB_N, 256, 0, stream>>>(counts, blocksums, row_ptr, cursor, NN);
    fill_csr<<<NB_E, 256, 0, stream>>>(src, dst, dinv, cursor, csr, EE);
    prep_w128<<<32, 256, 0, stream>>>(W1, Wf1);
    prep_w128<<<32, 256, 0, stream>>>(W2, Wf2);
    prep_w40<<<12, 256, 0, stream>>>(W3, Wf3);

    // ---- layer 1 ----
    gemm128_mfma<0><<<NB_G, 256, 0, stream>>>(x, Wf1, nullptr, nullptr, hB);
    agg128_bf16<<<NN / 4, 256, 0, stream>>>(hB, row_ptr, csr, dinv, b1, aF);
    zero_stats<<<1, 256, 0, stream>>>(stats);
    bn_stats<<<512, 128, 0, stream>>>(aF, stats, NN);
    finalize_scsh<<<1, 128, 0, stream>>>(stats, g1, be1, scsh);

    // ---- layer 2 (BN1 + residual + relu fused into A-fragment load) ----
    gemm128_mfma<1><<<NB_G, 256, 0, stream>>>(aF, Wf2, scsh, x, hB);
    agg128_bf16<<<NN / 4, 256, 0, stream>>>(hB, row_ptr, csr, dinv, b2, aF);
    zero_stats<<<1, 256, 0, stream>>>(stats);
    bn_stats<<<512, 128, 0, stream>>>(aF, stats, NN);
    finalize_scsh<<<1, 128, 0, stream>>>(stats, g2, be2, scsh);

    // ---- layer 3 (BN2 + relu fused into A-fragment load) ----
    gemm40_mfma<<<NB_G, 256, 0, stream>>>(aF, Wf3, scsh, h3);
    agg40_lsm<<<NN / 4, 256, 0, stream>>>(h3, row_ptr, csr, dinv, b3, out);
}